// Round 1
// baseline (152.984 us; speedup 1.0000x reference)
//
#include <hip/hip_runtime.h>
#include <hip/hip_bf16.h>

// Problem constants
#define B_SZ   16384
#define D_SZ   768
#define H_SZ   128
#define S_SZ   65536
#define E_SZ   7

// Packed GEMM geometry
// K layout: [0,768) h_t | [768,896) s_t | [896,1664) h_ctx | 1664..1666 sent | 1667 bias(1.0) | pad->1696
// N layout: [0,256) r,z (gi+gh summed) | [256,384) i_n | [384,512) h_n | [512,519) W_e | 519 W_s | pad->528
#define KTOT   1696
#define NTOT   528
#define NFR    33
#define BM     64
#define LDA_P  40   // 32 + 8 bf16 pad -> 80B stride, conflict-free ds_read_b128
#define LDB_P  40

typedef __attribute__((ext_vector_type(8))) short bf16x8;
typedef __attribute__((ext_vector_type(4))) float f32x4;

static __device__ __forceinline__ ushort f2bf(float v) {
    unsigned u = __float_as_uint(v);
    u = (u + 0x7FFFu + ((u >> 16) & 1u)) >> 16;   // RNE
    return (ushort)u;
}

// ---------------- pack W2 (bf16 [528][1696]) ----------------
__global__ __launch_bounds__(256) void pack_w2_kernel(
    const float* __restrict__ W_ih, const float* __restrict__ W_hh,
    const float* __restrict__ b_ih, const float* __restrict__ b_hh,
    const float* __restrict__ W_e,  const float* __restrict__ b_e,
    const float* __restrict__ W_s,  const float* __restrict__ b_s,
    ushort* __restrict__ W2)
{
    int idx = blockIdx.x * 256 + threadIdx.x;
    if (idx >= NTOT * KTOT) return;
    int n = idx / KTOT;
    int k = idx - n * KTOT;
    float v = 0.0f;
    if (n < 256) {                       // r,z rows: gi + gh summed
        if (k < 768)                        v = W_ih[(size_t)n * 771 + k];
        else if (k < 896)                   v = W_hh[(size_t)n * 128 + (k - 768)];
        else if (k >= 1664 && k < 1667)     v = W_ih[(size_t)n * 771 + 768 + (k - 1664)];
        else if (k == 1667)                 v = b_ih[n] + b_hh[n];
    } else if (n < 384) {                // i_n rows (W_ih rows 256..383)
        if (k < 768)                        v = W_ih[(size_t)n * 771 + k];
        else if (k >= 1664 && k < 1667)     v = W_ih[(size_t)n * 771 + 768 + (k - 1664)];
        else if (k == 1667)                 v = b_ih[n];
    } else if (n < 512) {                // h_n rows (W_hh rows 256..383)
        int g = n - 128;
        if (k >= 768 && k < 896)            v = W_hh[(size_t)g * 128 + (k - 768)];
        else if (k == 1667)                 v = b_hh[g];
    } else if (n < 520) {                // heads: z_t = [h_t(0:768) sent(768:771) s_t(771:899) h_ctx(899:1667)]
        int e = n - 512;
        const float* Wr = (e < E_SZ) ? (W_e + (size_t)e * 1667) : W_s;
        if (k < 768)                        v = Wr[k];
        else if (k < 896)                   v = Wr[771 + (k - 768)];
        else if (k < 1664)                  v = Wr[899 + (k - 896)];
        else if (k < 1667)                  v = Wr[768 + (k - 1664)];
        else if (k == 1667)                 v = (e < E_SZ) ? b_e[e] : b_s[0];
    }
    W2[idx] = f2bf(v);
}

// ---------------- winner (last-write-wins) ----------------
__global__ __launch_bounds__(256) void winner_kernel(const int* __restrict__ slot_ids,
                                                     int* __restrict__ winner)
{
    int b = blockIdx.x * 256 + threadIdx.x;
    if (b < B_SZ) atomicMax(&winner[slot_ids[b]], b);
}

// ---------------- staging / mfma helpers ----------------
template<int LO1, int HI1, int LO2, int HI2>
static __device__ __forceinline__ void stage_B(const ushort* __restrict__ W2,
                                               ushort* B_lds, int kbase, int tid)
{
    constexpr int NA1 = HI1 - LO1;
    constexpr int NA  = NA1 + (HI2 - LO2);
    for (int c = tid; c < NA * 64; c += 256) {
        int af = c >> 6;                 // active frag idx
        int w  = c & 63;                 // row(4b)*4 + kchunk(2b)
        int nf = (af < NA1) ? (LO1 + af) : (LO2 + (af - NA1));
        int n  = nf * 16 + (w >> 2);
        int kp = (w & 3) * 8;
        uint4 v = *reinterpret_cast<const uint4*>(W2 + (size_t)n * KTOT + kbase + kp);
        *reinterpret_cast<uint4*>(&B_lds[n * LDB_P + kp]) = v;
    }
}

template<int LO1, int HI1, int LO2, int HI2>
static __device__ __forceinline__ void mfma_frags(const ushort* A_lds, const ushort* B_lds,
                                                  f32x4* acc, int wave, int lane)
{
    const int col = lane & 15;
    const int kg  = (lane >> 4) * 8;
    bf16x8 a = *reinterpret_cast<const bf16x8*>(&A_lds[(wave * 16 + col) * LDA_P + kg]);
#pragma unroll
    for (int nf = LO1; nf < HI1; ++nf) {
        bf16x8 b = *reinterpret_cast<const bf16x8*>(&B_lds[(nf * 16 + col) * LDB_P + kg]);
        acc[nf] = __builtin_amdgcn_mfma_f32_16x16x32_bf16(a, b, acc[nf], 0, 0, 0);
    }
#pragma unroll
    for (int nf = LO2; nf < HI2; ++nf) {
        bf16x8 b = *reinterpret_cast<const bf16x8*>(&B_lds[(nf * 16 + col) * LDB_P + kg]);
        acc[nf] = __builtin_amdgcn_mfma_f32_16x16x32_bf16(a, b, acc[nf], 0, 0, 0);
    }
}

// ---------------- fused GEMM + GRU + heads + scatter ----------------
__global__ __launch_bounds__(256) void fused_kernel(
    const float* __restrict__ h_t,   const float* __restrict__ h_ctx,
    const float* __restrict__ sent,  const int* __restrict__ slot_ids,
    const float* __restrict__ memory,const ushort* __restrict__ W2,
    const int* __restrict__ winner,
    float* __restrict__ out_emo, float* __restrict__ out_shift, float* __restrict__ out_mem)
{
    __shared__ alignas(16) ushort A_lds[BM * LDA_P];
    __shared__ alignas(16) ushort B_lds[NTOT * LDB_P];

    const int tid  = threadIdx.x;
    const int wave = tid >> 6;
    const int lane = tid & 63;
    const int row0 = blockIdx.x * BM;
    const int arow = tid >> 2;          // 0..63
    const int kp   = (tid & 3) * 8;     // 0/8/16/24
    const int bidx = row0 + arow;

    f32x4 acc[NFR];
#pragma unroll
    for (int i = 0; i < NFR; ++i) { f32x4 z = {0.f, 0.f, 0.f, 0.f}; acc[i] = z; }

#define STAGE_A_FROM(PTR) do {                                                    \
        float4 v0 = *reinterpret_cast<const float4*>(PTR);                        \
        float4 v1 = *reinterpret_cast<const float4*>((PTR) + 4);                  \
        bf16x8 o;                                                                 \
        o[0]=(short)f2bf(v0.x); o[1]=(short)f2bf(v0.y);                           \
        o[2]=(short)f2bf(v0.z); o[3]=(short)f2bf(v0.w);                           \
        o[4]=(short)f2bf(v1.x); o[5]=(short)f2bf(v1.y);                           \
        o[6]=(short)f2bf(v1.z); o[7]=(short)f2bf(v1.w);                           \
        *reinterpret_cast<bf16x8*>(&A_lds[arow * LDA_P + kp]) = o;                \
    } while (0)

    // Phase 1: h_t (k 0..767). Active N-frags: rz+i_n [0,24) + heads [32,33)
    for (int step = 0; step < 24; ++step) {
        __syncthreads();
        { const float* s = h_t + (size_t)bidx * D_SZ + step * 32 + kp; STAGE_A_FROM(s); }
        stage_B<0, 24, 32, 33>(W2, B_lds, step * 32, tid);
        __syncthreads();
        mfma_frags<0, 24, 32, 33>(A_lds, B_lds, acc, wave, lane);
    }
    // Phase 2: s_t gather (k 768..895). Active: rz [0,16) + h_n+heads [24,33)
    for (int step = 0; step < 4; ++step) {
        __syncthreads();
        {
            int slot = slot_ids[bidx];
            const float* s = memory + (size_t)slot * H_SZ + step * 32 + kp;
            STAGE_A_FROM(s);
        }
        stage_B<0, 16, 24, 33>(W2, B_lds, 768 + step * 32, tid);
        __syncthreads();
        mfma_frags<0, 16, 24, 33>(A_lds, B_lds, acc, wave, lane);
    }
    // Phase 3: h_ctx (k 896..1663). Active: heads only [32,33)
    for (int step = 0; step < 24; ++step) {
        __syncthreads();
        { const float* s = h_ctx + (size_t)bidx * D_SZ + step * 32 + kp; STAGE_A_FROM(s); }
        stage_B<32, 33, 33, 33>(W2, B_lds, 896 + step * 32, tid);
        __syncthreads();
        mfma_frags<32, 33, 33, 33>(A_lds, B_lds, acc, wave, lane);
    }
    // Phase 4: tail (k 1664..1695): sent(3) + bias-one + zeros. Active: all
    {
        __syncthreads();
        bf16x8 o;
#pragma unroll
        for (int j = 0; j < 8; ++j) {
            int kk = kp + j;
            float v = (kk < 3) ? sent[(size_t)bidx * 3 + kk] : (kk == 3 ? 1.0f : 0.0f);
            o[j] = (short)f2bf(v);
        }
        *reinterpret_cast<bf16x8*>(&A_lds[arow * LDA_P + kp]) = o;
        stage_B<0, 33, 33, 33>(W2, B_lds, 1664, tid);
        __syncthreads();
        mfma_frags<0, 33, 33, 33>(A_lds, B_lds, acc, wave, lane);
    }

    // Epilogue: fully lane-local GRU + heads + winner-scatter.
    // D layout: col = lane&15, row = (lane>>4)*4 + reg
    const int col   = lane & 15;
    const int rbase = wave * 16 + (lane >> 4) * 4;
#pragma unroll
    for (int r = 0; r < 4; ++r) {
        const int row  = row0 + rbase + r;
        const int slot = slot_ids[row];
        const bool win = (winner[slot] == row);
#pragma unroll
        for (int nf = 0; nf < 8; ++nf) {
            const int j = nf * 16 + col;               // hidden index 0..127
            float rg  = acc[nf][r];                    // r-gate preact (biased)
            float zg  = acc[8 + nf][r];                // z-gate preact
            float inn = acc[16 + nf][r];               // i_n (biased b_ih)
            float hnn = acc[24 + nf][r];               // h_n (biased b_hh)
            rg = 1.0f / (1.0f + __expf(-rg));
            zg = 1.0f / (1.0f + __expf(-zg));
            float nn = tanhf(inn + rg * hnn);
            float h  = memory[(size_t)slot * H_SZ + j];  // exact f32 pre-update state
            float sn = (1.0f - zg) * nn + zg * h;
            if (win) out_mem[(size_t)slot * H_SZ + j] = sn;
        }
        float hv = acc[32][r];                         // heads frag (biased)
        if (col < E_SZ)       out_emo[(size_t)row * E_SZ + col] = hv;
        else if (col == E_SZ) out_shift[row] = hv;
    }
#undef STAGE_A_FROM
}

// ---------------- launch ----------------
extern "C" void kernel_launch(void* const* d_in, const int* in_sizes, int n_in,
                              void* d_out, int out_size, void* d_ws, size_t ws_size,
                              hipStream_t stream)
{
    const float* h_t     = (const float*)d_in[0];
    const float* h_ctx   = (const float*)d_in[1];
    const float* sent    = (const float*)d_in[2];
    const int*   slot_ids= (const int*)  d_in[3];
    const float* memory  = (const float*)d_in[4];
    const float* W_ih    = (const float*)d_in[5];
    const float* W_hh    = (const float*)d_in[6];
    const float* b_ih    = (const float*)d_in[7];
    const float* b_hh    = (const float*)d_in[8];
    const float* W_e     = (const float*)d_in[9];
    const float* b_e     = (const float*)d_in[10];
    const float* W_s     = (const float*)d_in[11];
    const float* b_s     = (const float*)d_in[12];

    float* out       = (float*)d_out;
    float* out_emo   = out;                                    // [B,7]
    float* out_shift = out + (size_t)B_SZ * E_SZ;              // [B]
    float* out_mem   = out + (size_t)B_SZ * E_SZ + B_SZ;       // [S,H]

    int*    winner = (int*)d_ws;                               // S ints
    ushort* W2     = (ushort*)((char*)d_ws + (size_t)S_SZ * sizeof(int));

    hipMemsetAsync(winner, 0xFF, (size_t)S_SZ * sizeof(int), stream);   // -1
    hipMemcpyAsync(out_mem, memory, (size_t)S_SZ * H_SZ * sizeof(float),
                   hipMemcpyDeviceToDevice, stream);

    pack_w2_kernel<<<(NTOT * KTOT + 255) / 256, 256, 0, stream>>>(
        W_ih, W_hh, b_ih, b_hh, W_e, b_e, W_s, b_s, W2);
    winner_kernel<<<B_SZ / 256, 256, 0, stream>>>(slot_ids, winner);
    fused_kernel<<<B_SZ / BM, 256, 0, stream>>>(
        h_t, h_ctx, sent, slot_ids, memory, W2, winner, out_emo, out_shift, out_mem);
}